// Round 7
// baseline (888.137 us; speedup 1.0000x reference)
//
#include <hip/hip_runtime.h>
#include <math.h>

#define TBL   (1u << 19)
#define TMASK (TBL - 1u)
#define PRIME1 2654435761u
#define PRIME2 805459861u

typedef float v2f __attribute__((ext_vector_type(2)));
typedef float v4f __attribute__((ext_vector_type(4)));

struct LevelParams {
    float    scale[16];
    unsigned res[16];
    unsigned dense[16];
};

__device__ __forceinline__ void corner_indices(
    float x, float y, float z, float s, unsigned res, unsigned dense,
    unsigned idx[8], float* wx, float* wy, float* wz)
{
    float px = __fadd_rn(__fmul_rn(x, s), 0.5f);
    float py = __fadd_rn(__fmul_rn(y, s), 0.5f);
    float pz = __fadd_rn(__fmul_rn(z, s), 0.5f);
    float fx = floorf(px), fy = floorf(py), fz = floorf(pz);
    *wx = px - fx; *wy = py - fy; *wz = pz - fz;
    unsigned gx = (unsigned)fx, gy = (unsigned)fy, gz = (unsigned)fz;

    if (dense) {
        const unsigned rm1 = res - 1u;
        unsigned cx0 = min(gx, rm1),   cx1 = min(gx + 1u, rm1);
        unsigned cy0 = min(gy, rm1),   cy1 = min(gy + 1u, rm1);
        unsigned cz0 = min(gz, rm1),   cz1 = min(gz + 1u, rm1);
        unsigned y0 = cy0 * res,       y1 = cy1 * res;
        unsigned z0 = cz0 * res * res, z1 = cz1 * res * res;
        idx[0] = cx0 + y0 + z0;  idx[1] = cx0 + y0 + z1;
        idx[2] = cx0 + y1 + z0;  idx[3] = cx0 + y1 + z1;
        idx[4] = cx1 + y0 + z0;  idx[5] = cx1 + y0 + z1;
        idx[6] = cx1 + y1 + z0;  idx[7] = cx1 + y1 + z1;
    } else {
        unsigned hx0 = gx,          hx1 = gx + 1u;
        unsigned hy0 = gy * PRIME1, hy1 = hy0 + PRIME1;
        unsigned hz0 = gz * PRIME2, hz1 = hz0 + PRIME2;
        idx[0] = (hx0 ^ hy0 ^ hz0) & TMASK;
        idx[1] = (hx0 ^ hy0 ^ hz1) & TMASK;
        idx[2] = (hx0 ^ hy1 ^ hz0) & TMASK;
        idx[3] = (hx0 ^ hy1 ^ hz1) & TMASK;
        idx[4] = (hx1 ^ hy0 ^ hz0) & TMASK;
        idx[5] = (hx1 ^ hy0 ^ hz1) & TMASK;
        idx[6] = (hx1 ^ hy1 ^ hz0) & TMASK;
        idx[7] = (hx1 ^ hy1 ^ hz1) & TMASK;
    }
}

// Paired 16B gather (proven R1: 544->477us). R5/R6 established the gather
// wall is a table-LINE-REQUEST RATE (~175k lines/us chip-wide), invariant
// to cache residency -- but only while concurrent table working set stays
// small enough to avoid the L3-BW wall (R6 fused, 128MB set: 2.47GB fetch,
// BW-bound at 3.6TB/s).
__device__ __forceinline__ v2f interp_level(
    const v4f* __restrict__ tab4,
    float x, float y, float z, float s, unsigned res, unsigned dense)
{
    unsigned idx[8];
    float wx, wy, wz;
    corner_indices(x, y, z, s, res, dense, idx, &wx, &wy, &wz);

    float wx0 = 1.f - wx, wy0 = 1.f - wy, wz0 = 1.f - wz;
    float wyz00 = wy0 * wz0, wyz01 = wy0 * wz;
    float wyz10 = wy  * wz0, wyz11 = wy  * wz;
    float cw0[4] = { wx0 * wyz00, wx0 * wyz01, wx0 * wyz10, wx0 * wyz11 };
    float cw1[4] = { wx  * wyz00, wx  * wyz01, wx  * wyz10, wx  * wyz11 };

    float f0 = 0.f, f1 = 0.f;
    #pragma unroll
    for (int k = 0; k < 4; ++k) {
        unsigned i0 = idx[k], i1 = idx[k + 4];
        v4f q0 = tab4[i0 >> 1];
        v4f q1 = tab4[i1 >> 1];
        float a0 = (i0 & 1u) ? q0.z : q0.x;
        float b0 = (i0 & 1u) ? q0.w : q0.y;
        float a1 = (i1 & 1u) ? q1.z : q1.x;
        float b1 = (i1 & 1u) ? q1.w : q1.y;
        f0 = fmaf(cw0[k], a0, f0);
        f1 = fmaf(cw0[k], b0, f1);
        f0 = fmaf(cw1[k], a1, f0);
        f1 = fmaf(cw1[k], b1, f1);
    }
    v2f r; r.x = f0; r.y = f1;
    return r;
}

// ---------- Split-fused: 8 levels per kernel, direct half-row output ------
// HALF=0: levels 0..7 -> out floats [0,16) of each row (first 64B line).
// HALF=1: levels 8..15 -> out floats [16,32) (second 64B line).
// Concurrent table working set: 16MB / 32MB (vs 128MB in R6's fused) ->
// stays off the L3-BW wall. No ws, no separate transpose pass. LDS
// 256x17 floats = 17.4KB -> 8 blocks/CU.
template <int HALF>
__global__ __launch_bounds__(256, 8) void enc_half(
    const float* __restrict__ coords,
    const float* __restrict__ table,
    float* __restrict__ out,
    LevelParams lp, unsigned n)
{
    __shared__ float lds[256 * 17];
    const unsigned t  = threadIdx.x;
    const unsigned p0 = blockIdx.x * 256u;
    const unsigned p  = p0 + t;

    float x = 0.f, y = 0.f, z = 0.f;
    if (p < n) {
        x = coords[3ull * p + 0];
        y = coords[3ull * p + 1];
        z = coords[3ull * p + 2];
    }

    #pragma unroll 2
    for (int li = 0; li < 8; ++li) {
        const int l = HALF * 8 + li;
        const v4f* __restrict__ tab4 =
            (const v4f*)(table + (size_t)l * (2u * TBL));
        v2f r = interp_level(tab4, x, y, z, lp.scale[l], lp.res[l],
                             lp.dense[l]);
        lds[t * 17u + 2u * (unsigned)li]      = r.x;
        lds[t * 17u + 2u * (unsigned)li + 1u] = r.y;
    }
    __syncthreads();

    // Each point's half-row = 16 floats = one complete 64B line.
    // j = i*256+t covers 1024 v4f: pt = j>>2 (0..255), c = j&3.
    // Address out4[(p0+pt)*8 + HALF*4 + c]: every line written fully
    // (4 consecutive v4f by 4 consecutive lanes) -> no partial-line HBM.
    v4f* __restrict__ out4 = (v4f*)out;
    const size_t total4 = (size_t)n * 8u;
    #pragma unroll
    for (int i = 0; i < 4; ++i) {
        unsigned j  = (unsigned)i * 256u + t;
        unsigned pt = j >> 2, c = j & 3u;
        size_t o = (size_t)(p0 + pt) * 8u + (unsigned)(HALF * 4) + c;
        if (o < total4) {
            v4f q;
            q.x = lds[pt * 17u + c * 4u + 0u];
            q.y = lds[pt * 17u + c * 4u + 1u];
            q.z = lds[pt * 17u + c * 4u + 2u];
            q.w = lds[pt * 17u + c * 4u + 3u];
            __builtin_nontemporal_store(q, out4 + o);
        }
    }
}

extern "C" void kernel_launch(void* const* d_in, const int* in_sizes, int n_in,
                              void* d_out, int out_size, void* d_ws, size_t ws_size,
                              hipStream_t stream) {
    (void)n_in; (void)out_size; (void)d_ws; (void)ws_size;
    const float* coords = (const float*)d_in[0];
    const float* table  = (const float*)d_in[1];
    float* out = (float*)d_out;

    LevelParams lp;
    for (int l = 0; l < 16; ++l) {
        double scale = 16.0 * pow(1.4472692012786865, (double)l) - 1.0;
        int res = (int)ceil(scale) + 1;
        lp.scale[l] = (float)scale;
        lp.res[l]   = (unsigned)res;
        long long r3 = (long long)res * res * res;
        lp.dense[l] = (r3 <= (long long)TBL) ? 1u : 0u;
    }

    unsigned n = (unsigned)(in_sizes[0] / 3);
    unsigned chunks = (n + 255u) / 256u;

    hipLaunchKernelGGL(enc_half<0>, dim3(chunks), dim3(256), 0, stream,
                       coords, table, out, lp, n);
    hipLaunchKernelGGL(enc_half<1>, dim3(chunks), dim3(256), 0, stream,
                       coords, table, out, lp, n);
}

// Round 9
// 630.310 us; speedup vs baseline: 1.4090x; 1.4090x over previous
//
#include <hip/hip_runtime.h>
#include <math.h>

#define TBL   (1u << 19)
#define TMASK (TBL - 1u)
#define PRIME1 2654435761u
#define PRIME2 805459861u

typedef float v2f __attribute__((ext_vector_type(2)));
typedef float v4f __attribute__((ext_vector_type(4)));

struct LevelParams {
    float    scale[16];
    unsigned res[16];
    unsigned dense[16];
};

__device__ __forceinline__ void split_pos(
    float x, float y, float z, float s,
    unsigned* gx, unsigned* gy, unsigned* gz,
    float* wx, float* wy, float* wz)
{
    float px = __fadd_rn(__fmul_rn(x, s), 0.5f);
    float py = __fadd_rn(__fmul_rn(y, s), 0.5f);
    float pz = __fadd_rn(__fmul_rn(z, s), 0.5f);
    float fx = floorf(px), fy = floorf(py), fz = floorf(pz);
    *wx = px - fx; *wy = py - fy; *wz = pz - fz;
    *gx = (unsigned)fx; *gy = (unsigned)fy; *gz = (unsigned)fz;
}

__device__ __forceinline__ void corner_w(
    float wx, float wy, float wz, float cw0[4], float cw1[4])
{
    float wx0 = 1.f - wx, wy0 = 1.f - wy, wz0 = 1.f - wz;
    float wyz00 = wy0 * wz0, wyz01 = wy0 * wz;
    float wyz10 = wy  * wz0, wyz11 = wy  * wz;
    cw0[0] = wx0 * wyz00; cw0[1] = wx0 * wyz01;
    cw0[2] = wx0 * wyz10; cw0[3] = wx0 * wyz11;
    cw1[0] = wx  * wyz00; cw1[1] = wx  * wyz01;
    cw1[2] = wx  * wyz10; cw1[3] = wx  * wyz11;
}

// Dense levels: 8 paired-16B gathers (small tables, L2-resident, ~19us/level).
__device__ __forceinline__ v2f interp_dense(
    const v4f* __restrict__ tab4,
    float x, float y, float z, float s, unsigned res)
{
    unsigned gx, gy, gz; float wx, wy, wz;
    split_pos(x, y, z, s, &gx, &gy, &gz, &wx, &wy, &wz);
    const unsigned rm1 = res - 1u;
    unsigned cx0 = min(gx, rm1),   cx1 = min(gx + 1u, rm1);
    unsigned cy0 = min(gy, rm1),   cy1 = min(gy + 1u, rm1);
    unsigned cz0 = min(gz, rm1),   cz1 = min(gz + 1u, rm1);
    unsigned y0 = cy0 * res,       y1 = cy1 * res;
    unsigned z0 = cz0 * res * res, z1 = cz1 * res * res;
    unsigned i0[4] = { cx0+y0+z0, cx0+y0+z1, cx0+y1+z0, cx0+y1+z1 };
    unsigned i1[4] = { cx1+y0+z0, cx1+y0+z1, cx1+y1+z0, cx1+y1+z1 };

    float cw0[4], cw1[4];
    corner_w(wx, wy, wz, cw0, cw1);
    float f0 = 0.f, f1 = 0.f;
    #pragma unroll
    for (int k = 0; k < 4; ++k) {
        v4f q0 = tab4[i0[k] >> 1];
        v4f q1 = tab4[i1[k] >> 1];
        float a0 = (i0[k] & 1u) ? q0.z : q0.x;
        float b0 = (i0[k] & 1u) ? q0.w : q0.y;
        float a1 = (i1[k] & 1u) ? q1.z : q1.x;
        float b1 = (i1[k] & 1u) ? q1.w : q1.y;
        f0 = fmaf(cw0[k], a0, f0);
        f1 = fmaf(cw0[k], b0, f1);
        f0 = fmaf(cw1[k], a1, f0);
        f1 = fmaf(cw1[k], b1, f1);
    }
    v2f r; r.x = f0; r.y = f1;
    return r;
}

// Hashed levels. FAST PATH: when gx is even, (gx+1) == gx^1, so for all 4
// y/z combos idx_x1 = idx_x0 ^ 1 -- the x-pair is INSIDE the aligned 16B
// pair we already load. Half the points need only 4 loads instead of 8.
// The per-lane branch splits the wave; TA/L2-request cost scales with
// active lanes per load, so total address count drops ~25% (R5 showed the
// gather wall is request-rate, not line-fetch -> this attacks it directly).
__device__ __forceinline__ v2f interp_hashed(
    const v4f* __restrict__ tab4,
    float x, float y, float z, float s)
{
    unsigned gx, gy, gz; float wx, wy, wz;
    split_pos(x, y, z, s, &gx, &gy, &gz, &wx, &wy, &wz);
    unsigned hy0 = gy * PRIME1, hy1 = hy0 + PRIME1;
    unsigned hz0 = gz * PRIME2, hz1 = hz0 + PRIME2;
    unsigned b0[4] = { (gx^hy0^hz0)&TMASK, (gx^hy0^hz1)&TMASK,
                       (gx^hy1^hz0)&TMASK, (gx^hy1^hz1)&TMASK };

    float cw0[4], cw1[4];
    corner_w(wx, wy, wz, cw0, cw1);
    float f0 = 0.f, f1 = 0.f;

    if ((gx & 1u) == 0u) {
        // 4 loads: each 16B pair holds BOTH x0 (idx) and x1 (idx^1).
        #pragma unroll
        for (int k = 0; k < 4; ++k) {
            unsigned i0 = b0[k];
            v4f q = tab4[i0 >> 1];
            bool odd = (i0 & 1u) != 0u;
            float a0 = odd ? q.z : q.x, c0 = odd ? q.w : q.y;
            float a1 = odd ? q.x : q.z, c1 = odd ? q.y : q.w;
            f0 = fmaf(cw0[k], a0, f0);
            f1 = fmaf(cw0[k], c0, f1);
            f0 = fmaf(cw1[k], a1, f0);
            f1 = fmaf(cw1[k], c1, f1);
        }
    } else {
        unsigned gx1 = gx + 1u;
        unsigned b1[4] = { (gx1^hy0^hz0)&TMASK, (gx1^hy0^hz1)&TMASK,
                           (gx1^hy1^hz0)&TMASK, (gx1^hy1^hz1)&TMASK };
        #pragma unroll
        for (int k = 0; k < 4; ++k) {
            v4f q0 = tab4[b0[k] >> 1];
            v4f q1 = tab4[b1[k] >> 1];
            float a0 = (b0[k] & 1u) ? q0.z : q0.x;
            float c0 = (b0[k] & 1u) ? q0.w : q0.y;
            float a1 = (b1[k] & 1u) ? q1.z : q1.x;
            float c1 = (b1[k] & 1u) ? q1.w : q1.y;
            f0 = fmaf(cw0[k], a0, f0);
            f1 = fmaf(cw0[k], c0, f1);
            f0 = fmaf(cw1[k], a1, f0);
            f1 = fmaf(cw1[k], c1, f1);
        }
    }
    v2f r; r.x = f0; r.y = f1;
    return r;
}

// ---------- Pass A: all 16 levels, blockIdx.y = level ----------
// Level as the OUTER grid dim is load-bearing: dispatch order keeps only
// ~2 tables active chip-wide (R4: 34.6us/level, FETCH 42MB/level). In-kernel
// level loops activate all tables at once -> L2 thrash -> 3.8TB/s fetch
// wall (R6: 2.47GB, R7: 1.7GB/half). NT ws stores keep tables in cache.
__global__ __launch_bounds__(256, 8) void pass_a(
    const float* __restrict__ coords,
    const float* __restrict__ table,
    v2f* __restrict__ ws,            // [16][N] float2, level-major
    LevelParams lp, unsigned n)
{
    const unsigned l = blockIdx.y;
    const unsigned p = blockIdx.x * 256u + threadIdx.x;
    if (p >= n) return;

    const float x = coords[3ull * p + 0];
    const float y = coords[3ull * p + 1];
    const float z = coords[3ull * p + 2];

    const v4f* __restrict__ tab4 = (const v4f*)(table + (size_t)l * (2u * TBL));
    v2f r = lp.dense[l]
        ? interp_dense (tab4, x, y, z, lp.scale[l], lp.res[l])
        : interp_hashed(tab4, x, y, z, lp.scale[l]);
    __builtin_nontemporal_store(r, ws + (size_t)l * n + p);
}

// ---------- Pass B: ws[16][N] v2f -> out[N][32], 512 pts/block ----------
// Policy experiment: CACHED v4f loads (2 points per load) instead of NT v2f
// (R0/R5 pass_b stuck at 1.5TB/s). 2-round 33-stride LDS transpose
// (33.8KB -> 4 blocks/CU), NT v4f output stores.
__global__ __launch_bounds__(256, 4) void pass_b(
    const v2f* __restrict__ ws,
    float* __restrict__ out, unsigned n)
{
    __shared__ float lds[256 * 33];
    const unsigned t  = threadIdx.x;
    const unsigned p0 = blockIdx.x * 512u;
    const unsigned pb = p0 + 2u * t;         // this thread's 2 points

    v4f v[16];
    #pragma unroll
    for (int l = 0; l < 16; ++l) {
        v4f q = {0.f, 0.f, 0.f, 0.f};
        if (pb + 1u < n) {
            q = *(const v4f*)(ws + (size_t)l * n + pb);
        } else if (pb < n) {
            v2f h = ws[(size_t)l * n + pb];
            q.x = h.x; q.y = h.y;
        }
        v[l] = q;
    }

    v4f* __restrict__ out4 = (v4f*)out;
    const size_t total4 = (size_t)n * 8u;

    #pragma unroll
    for (int r = 0; r < 2; ++r) {
        __syncthreads();
        // threads 128r..128r+127 hold points [p0+256r, p0+256r+256)
        if ((t >> 7) == (unsigned)r) {
            const unsigned lp0 = 2u * (t & 127u);      // 0..254 even
            #pragma unroll
            for (int l = 0; l < 16; ++l) {
                lds[lp0 * 33u + 2u * l]            = v[l].x;
                lds[lp0 * 33u + 2u * l + 1u]       = v[l].y;
                lds[(lp0 + 1u) * 33u + 2u * l]     = v[l].z;
                lds[(lp0 + 1u) * 33u + 2u * l + 1u]= v[l].w;
            }
        }
        __syncthreads();
        // 256 rows x 8 v4f = 2048 stores, 8 per thread, coalesced NT.
        const unsigned pr0 = p0 + 256u * (unsigned)r;
        #pragma unroll
        for (int i = 0; i < 8; ++i) {
            unsigned j  = (unsigned)i * 256u + t;
            unsigned pt = j >> 3, c = (j & 7u);
            size_t o = (size_t)(pr0 + pt) * 8u + c;
            if (o < total4) {
                v4f q;
                q.x = lds[pt * 33u + c * 4u + 0u];
                q.y = lds[pt * 33u + c * 4u + 1u];
                q.z = lds[pt * 33u + c * 4u + 2u];
                q.w = lds[pt * 33u + c * 4u + 3u];
                __builtin_nontemporal_store(q, out4 + o);
            }
        }
    }
}

// ---------- Fallback: single-kernel (if ws too small) ----------
__global__ __launch_bounds__(256, 4) void hashgrid_enc(
    const float* __restrict__ coords,
    const float* __restrict__ table,
    float* __restrict__ out,
    LevelParams lp, unsigned n)
{
    __shared__ float lds[256 * 33];
    const unsigned t = threadIdx.x;
    const unsigned p = blockIdx.x * 256u + t;

    float x = 0.f, y = 0.f, z = 0.f;
    if (p < n) {
        x = coords[3ull * p + 0];
        y = coords[3ull * p + 1];
        z = coords[3ull * p + 2];
    }

    #pragma unroll 2
    for (int l = 0; l < 16; ++l) {
        const v4f* __restrict__ tab4 = (const v4f*)(table + (size_t)l * (2u * TBL));
        v2f r = lp.dense[l]
            ? interp_dense (tab4, x, y, z, lp.scale[l], lp.res[l])
            : interp_hashed(tab4, x, y, z, lp.scale[l]);
        lds[t * 33u + 2u * l]      = r.x;
        lds[t * 33u + 2u * l + 1u] = r.y;
    }
    __syncthreads();

    const size_t base  = (size_t)blockIdx.x * 8192u;
    const size_t total = (size_t)n * 32u;
    #pragma unroll
    for (int i = 0; i < 32; ++i) {
        size_t j = (size_t)i * 256u + t;
        size_t o = base + j;
        if (o < total)
            out[o] = lds[(unsigned)(j >> 5) * 33u + ((unsigned)j & 31u)];
    }
}

extern "C" void kernel_launch(void* const* d_in, const int* in_sizes, int n_in,
                              void* d_out, int out_size, void* d_ws, size_t ws_size,
                              hipStream_t stream) {
    (void)n_in; (void)out_size;
    const float* coords = (const float*)d_in[0];
    const float* table  = (const float*)d_in[1];
    float* out = (float*)d_out;

    LevelParams lp;
    for (int l = 0; l < 16; ++l) {
        double scale = 16.0 * pow(1.4472692012786865, (double)l) - 1.0;
        int res = (int)ceil(scale) + 1;
        lp.scale[l] = (float)scale;
        lp.res[l]   = (unsigned)res;
        long long r3 = (long long)res * res * res;
        lp.dense[l] = (r3 <= (long long)TBL) ? 1u : 0u;
    }

    unsigned n = (unsigned)(in_sizes[0] / 3);
    unsigned chunks = (n + 255u) / 256u;
    size_t ws_needed = (size_t)16 * n * sizeof(v2f);

    if (ws_size >= ws_needed) {
        v2f* ws = (v2f*)d_ws;
        hipLaunchKernelGGL(pass_a, dim3(chunks, 16), dim3(256), 0, stream,
                           coords, table, ws, lp, n);
        unsigned chunks_b = (n + 511u) / 512u;
        hipLaunchKernelGGL(pass_b, dim3(chunks_b), dim3(256), 0, stream,
                           ws, out, n);
    } else {
        hipLaunchKernelGGL(hashgrid_enc, dim3(chunks), dim3(256), 0, stream,
                           coords, table, out, lp, n);
    }
}